// Round 1
// baseline (9570.190 us; speedup 1.0000x reference)
//
#include <hip/hip_runtime.h>
#include <float.h>
#include <math.h>

// Problem constants (fixed by the reference)
constexpr int Cc = 19;    // classes
constexpr int Kk = 50;    // pca dim
constexpr int Dd = 256;   // feature dim

constexpr int TPB  = 256;        // threads per block
constexpr int PXT  = 4;          // pixels per thread (LDS amortization factor)
constexpr int PXB  = TPB * PXT;  // 1024 pixels per block
constexpr int NGRP = 4;          // class groups: {0-4,5-9,10-14,15-18}

// ---------------------------------------------------------------------------
// Prep: per (c,k) compute rv = 1/sqrt(var), bc = mean_proj*rv + mu
// ---------------------------------------------------------------------------
__global__ void prep_kernel(const float* __restrict__ pca_mean,
                            const float* __restrict__ comps,
                            const float* __restrict__ var,
                            const float* __restrict__ mu,
                            float* __restrict__ w_rv,
                            float* __restrict__ w_bc) {
  int c = blockIdx.x;
  int k = threadIdx.x;
  if (k >= Kk) return;
  const float* m  = pca_mean + (size_t)c * Dd;
  const float* cp = comps + ((size_t)(c * Kk + k)) * Dd;
  float s = 0.f;
  #pragma unroll 8
  for (int d = 0; d < Dd; ++d) s = fmaf(m[d], cp[d], s);
  float rv = 1.0f / sqrtf(var[c * Kk + k]);
  w_rv[c * Kk + k] = rv;
  w_bc[c * Kk + k] = fmaf(s, rv, mu[c * Kk + k]);
}

// ---------------------------------------------------------------------------
// Init output to +FLT_MAX so class-group blocks can atomicMin into it.
// ---------------------------------------------------------------------------
__global__ void init_kernel(float* __restrict__ out, int n) {
  int i = blockIdx.x * blockDim.x + threadIdx.x;
  if (i < n) out[i] = FLT_MAX;
}

// ---------------------------------------------------------------------------
// Main: 4 pixels per thread (each LDS broadcast read feeds 16 FMAs instead
// of 4 -> LDS traffic /4). Classes split into NGRP groups across blocks so
// the grid still fills 256 CUs; per-pixel combine via atomicMin on float
// bits (dist >= 0 since cov_inv is SPD, so uint order == float order).
// ---------------------------------------------------------------------------
__global__ __launch_bounds__(TPB, 2) void outlier_kernel(
    const float* __restrict__ feats,
    const float* __restrict__ comps,
    const float* __restrict__ cov_inv,
    const float* __restrict__ w_rv,
    const float* __restrict__ w_bc,
    float* __restrict__ out, int n, int px_tiles) {
  __shared__ float sC[Kk * Dd];   // 51200 B  comps[c]
  __shared__ float sM[Kk * Kk];   // 10000 B  cov_inv[c]
  __shared__ float srv[Kk];
  __shared__ float sb[Kk];

  const int tid  = threadIdx.x;
  const int tile = blockIdx.x % px_tiles;   // tile's 4 group-blocks are 128
  const int grp  = blockIdx.x / px_tiles;   // apart -> same XCD (128%8==0)
  const int c0 = grp * 5;
  const int c1 = min(c0 + 5, Cc);

  const int p0 = tile * PXB + tid;  // pixels p0, p0+256, p0+512, p0+768

  // clamped row indices (grid is exact for N=131072; guards for safety)
  const int r0 = (p0           < n) ? p0           : 0;
  const int r1 = (p0 + TPB     < n) ? p0 + TPB     : 0;
  const int r2 = (p0 + 2 * TPB < n) ? p0 + 2 * TPB : 0;
  const int r3 = (p0 + 3 * TPB < n) ? p0 + 3 * TPB : 0;
  const float4* __restrict__ F = (const float4*)feats;
  const unsigned b0 = (unsigned)r0 * (Dd / 4);
  const unsigned b1 = (unsigned)r1 * (Dd / 4);
  const unsigned b2 = (unsigned)r2 * (Dd / 4);
  const unsigned b3 = (unsigned)r3 * (Dd / 4);

  float dmin0 = FLT_MAX, dmin1 = FLT_MAX, dmin2 = FLT_MAX, dmin3 = FLT_MAX;

  for (int c = c0; c < c1; ++c) {
    __syncthreads();  // previous class compute done before overwriting LDS
    {
      const float4* src = (const float4*)(comps + (size_t)c * Kk * Dd);
      float4* dst = (float4*)sC;
      for (int i = tid; i < (Kk * Dd) / 4; i += TPB) dst[i] = src[i];
    }
    {
      const float4* src = (const float4*)(cov_inv + (size_t)c * Kk * Kk);
      float4* dst = (float4*)sM;
      for (int i = tid; i < (Kk * Kk) / 4; i += TPB) dst[i] = src[i];
    }
    if (tid < Kk) {
      srv[tid] = w_rv[c * Kk + tid];
      sb[tid]  = w_bc[c * Kk + tid];
    }
    __syncthreads();

    // Projection: z{p}[k] = comps[c,k,:] . feats[p,:]
    float z0[Kk], z1[Kk], z2[Kk], z3[Kk];
    #pragma unroll
    for (int k = 0; k < Kk; ++k) { z0[k] = 0.f; z1[k] = 0.f; z2[k] = 0.f; z3[k] = 0.f; }

    for (int dc = 0; dc < Dd / 4; ++dc) {
      float4 fa = F[b0 + dc];
      float4 fb = F[b1 + dc];
      float4 fc = F[b2 + dc];
      float4 fd = F[b3 + dc];
      #pragma unroll
      for (int k = 0; k < Kk; ++k) {
        float4 r = ((const float4*)(sC + k * Dd))[dc];  // LDS broadcast
        float t0 = fmaf(r.x, fa.x, z0[k]); t0 = fmaf(r.y, fa.y, t0);
        t0 = fmaf(r.z, fa.z, t0);          z0[k] = fmaf(r.w, fa.w, t0);
        float t1 = fmaf(r.x, fb.x, z1[k]); t1 = fmaf(r.y, fb.y, t1);
        t1 = fmaf(r.z, fb.z, t1);          z1[k] = fmaf(r.w, fb.w, t1);
        float t2 = fmaf(r.x, fc.x, z2[k]); t2 = fmaf(r.y, fc.y, t2);
        t2 = fmaf(r.z, fc.z, t2);          z2[k] = fmaf(r.w, fc.w, t2);
        float t3 = fmaf(r.x, fd.x, z3[k]); t3 = fmaf(r.y, fd.y, t3);
        t3 = fmaf(r.z, fd.z, t3);          z3[k] = fmaf(r.w, fd.w, t3);
      }
    }

    // v = z*rv - (mean_proj*rv + mu)
    #pragma unroll
    for (int k = 0; k < Kk; ++k) {
      float rv = srv[k], bc = sb[k];
      z0[k] = fmaf(z0[k], rv, -bc);
      z1[k] = fmaf(z1[k], rv, -bc);
      z2[k] = fmaf(z2[k], rv, -bc);
      z3[k] = fmaf(z3[k], rv, -bc);
    }

    // dist_p = v_p^T M v_p
    float d0 = 0.f, d1 = 0.f, d2 = 0.f, d3 = 0.f;
    #pragma unroll
    for (int k = 0; k < Kk; ++k) {
      float s0 = 0.f, s1 = 0.f, s2 = 0.f, s3 = 0.f;
      const float2* row = (const float2*)(sM + k * Kk);  // 8B aligned (k*200)
      #pragma unroll
      for (int l = 0; l < Kk / 2; ++l) {
        float2 m2 = row[l];
        s0 = fmaf(m2.x, z0[2 * l], s0); s0 = fmaf(m2.y, z0[2 * l + 1], s0);
        s1 = fmaf(m2.x, z1[2 * l], s1); s1 = fmaf(m2.y, z1[2 * l + 1], s1);
        s2 = fmaf(m2.x, z2[2 * l], s2); s2 = fmaf(m2.y, z2[2 * l + 1], s2);
        s3 = fmaf(m2.x, z3[2 * l], s3); s3 = fmaf(m2.y, z3[2 * l + 1], s3);
      }
      d0 = fmaf(z0[k], s0, d0);
      d1 = fmaf(z1[k], s1, d1);
      d2 = fmaf(z2[k], s2, d2);
      d3 = fmaf(z3[k], s3, d3);
    }
    dmin0 = fminf(dmin0, d0);
    dmin1 = fminf(dmin1, d1);
    dmin2 = fminf(dmin2, d2);
    dmin3 = fminf(dmin3, d3);
  }

  // Combine class groups: dists >= 0, so uint compare == float compare.
  unsigned* uo = (unsigned*)out;
  if (p0           < n) atomicMin(uo + p0,           __float_as_uint(dmin0));
  if (p0 + TPB     < n) atomicMin(uo + p0 + TPB,     __float_as_uint(dmin1));
  if (p0 + 2 * TPB < n) atomicMin(uo + p0 + 2 * TPB, __float_as_uint(dmin2));
  if (p0 + 3 * TPB < n) atomicMin(uo + p0 + 3 * TPB, __float_as_uint(dmin3));
}

extern "C" void kernel_launch(void* const* d_in, const int* in_sizes, int n_in,
                              void* d_out, int out_size, void* d_ws, size_t ws_size,
                              hipStream_t stream) {
  const float* feats    = (const float*)d_in[0];
  const float* pca_mean = (const float*)d_in[1];
  const float* comps    = (const float*)d_in[2];
  const float* var      = (const float*)d_in[3];
  const float* mu       = (const float*)d_in[4];
  const float* cov_inv  = (const float*)d_in[5];
  float* out = (float*)d_out;

  float* w_rv = (float*)d_ws;
  float* w_bc = w_rv + Cc * Kk;

  const int n = in_sizes[0] / Dd;  // 131072 pixels

  prep_kernel<<<Cc, 64, 0, stream>>>(pca_mean, comps, var, mu, w_rv, w_bc);
  init_kernel<<<(n + TPB - 1) / TPB, TPB, 0, stream>>>(out, n);

  const int px_tiles = (n + PXB - 1) / PXB;  // 128
  outlier_kernel<<<px_tiles * NGRP, TPB, 0, stream>>>(feats, comps, cov_inv,
                                                      w_rv, w_bc, out, n,
                                                      px_tiles);
}

// Round 2
// 4754.239 us; speedup vs baseline: 2.0130x; 2.0130x over previous
//
#include <hip/hip_runtime.h>
#include <float.h>
#include <math.h>

// Problem constants (fixed by the reference)
constexpr int Cc = 19;    // classes
constexpr int Kk = 50;    // pca dim
constexpr int Dd = 256;   // feature dim

constexpr int TPB = 256;

// ---------------------------------------------------------------------------
// Prep: per (c,k) compute rv = 1/sqrt(var), bc = mean_proj*rv + mu
// ---------------------------------------------------------------------------
__global__ void prep_kernel(const float* __restrict__ pca_mean,
                            const float* __restrict__ comps,
                            const float* __restrict__ var,
                            const float* __restrict__ mu,
                            float* __restrict__ w_rv,
                            float* __restrict__ w_bc) {
  int c = blockIdx.x;
  int k = threadIdx.x;
  if (k >= Kk) return;
  const float* m  = pca_mean + (size_t)c * Dd;
  const float* cp = comps + ((size_t)(c * Kk + k)) * Dd;
  float s = 0.f;
  #pragma unroll 8
  for (int d = 0; d < Dd; ++d) s = fmaf(m[d], cp[d], s);
  float rv = 1.0f / sqrtf(var[c * Kk + k]);
  w_rv[c * Kk + k] = rv;
  w_bc[c * Kk + k] = fmaf(s, rv, mu[c * Kk + k]);
}

// ---------------------------------------------------------------------------
// Main: one pixel per thread, ZERO LDS. All class data (comps rows, cov_inv
// rows, rv/bc) is wave-uniform -> compiler promotes those loads to
// s_load_dwordxN through the scalar cache; inner FMAs are v_fmac v,s,v.
// Per-thread state: z[50] + 16-float feats chunk (~90 VGPR, no spill).
// Feats re-read per class from L2/L3 (feats = 134 MB, fits L3).
// ---------------------------------------------------------------------------
__global__ __launch_bounds__(TPB) void outlier_kernel(
    const float* __restrict__ feats,
    const float* __restrict__ comps,
    const float* __restrict__ cov_inv,
    const float* __restrict__ w_rv,
    const float* __restrict__ w_bc,
    float* __restrict__ out, int n) {
  const int p = blockIdx.x * TPB + threadIdx.x;
  if (p >= n) return;
  const float4* __restrict__ F = (const float4*)(feats + (size_t)p * Dd);

  float dmin = FLT_MAX;

  #pragma unroll 1          // keep class body out of I$ blowup
  for (int c = 0; c < Cc; ++c) {
    const float4* __restrict__ cb =
        (const float4*)(comps + (size_t)c * Kk * Dd);   // uniform base

    // Projection: z[k] = comps[c,k,:] . feats[p,:]
    float z[Kk];
    #pragma unroll
    for (int k = 0; k < Kk; ++k) z[k] = 0.f;

    #pragma unroll 2        // modest pipelining without I$ blowup
    for (int dc = 0; dc < Dd / 4; dc += 4) {
      // 16 floats of this pixel's feats row resident in VGPRs
      float4 fa = F[dc];
      float4 fb = F[dc + 1];
      float4 fc = F[dc + 2];
      float4 fd = F[dc + 3];
      #pragma unroll        // z[] is register-indexed: must fully unroll
      for (int k = 0; k < Kk; ++k) {
        const float4* row = cb + k * (Dd / 4) + dc;  // uniform -> s_load
        float4 r0 = row[0];
        float4 r1 = row[1];
        float4 r2 = row[2];
        float4 r3 = row[3];
        float t = z[k];
        t = fmaf(r0.x, fa.x, t); t = fmaf(r0.y, fa.y, t);
        t = fmaf(r0.z, fa.z, t); t = fmaf(r0.w, fa.w, t);
        t = fmaf(r1.x, fb.x, t); t = fmaf(r1.y, fb.y, t);
        t = fmaf(r1.z, fb.z, t); t = fmaf(r1.w, fb.w, t);
        t = fmaf(r2.x, fc.x, t); t = fmaf(r2.y, fc.y, t);
        t = fmaf(r2.z, fc.z, t); t = fmaf(r2.w, fc.w, t);
        t = fmaf(r3.x, fd.x, t); t = fmaf(r3.y, fd.y, t);
        t = fmaf(r3.z, fd.z, t); t = fmaf(r3.w, fd.w, t);
        z[k] = t;
      }
    }

    // v = z*rv - (mean_proj*rv + mu)   (rv/bc uniform scalar loads)
    #pragma unroll
    for (int k = 0; k < Kk; ++k) {
      float rv = w_rv[c * Kk + k];
      float bc = w_bc[c * Kk + k];
      z[k] = fmaf(z[k], rv, -bc);
    }

    // dist = v^T M v  (M rows uniform -> scalar loads)
    float dist = 0.f;
    #pragma unroll
    for (int k = 0; k < Kk; ++k) {
      const float2* row =
          (const float2*)(cov_inv + ((size_t)c * Kk + k) * Kk);  // 8B aligned
      float s = 0.f;
      #pragma unroll
      for (int l = 0; l < Kk / 2; ++l) {
        float2 m2 = row[l];
        s = fmaf(m2.x, z[2 * l], s);
        s = fmaf(m2.y, z[2 * l + 1], s);
      }
      dist = fmaf(z[k], s, dist);
    }
    dmin = fminf(dmin, dist);
  }

  out[p] = dmin;
}

extern "C" void kernel_launch(void* const* d_in, const int* in_sizes, int n_in,
                              void* d_out, int out_size, void* d_ws, size_t ws_size,
                              hipStream_t stream) {
  const float* feats    = (const float*)d_in[0];
  const float* pca_mean = (const float*)d_in[1];
  const float* comps    = (const float*)d_in[2];
  const float* var      = (const float*)d_in[3];
  const float* mu       = (const float*)d_in[4];
  const float* cov_inv  = (const float*)d_in[5];
  float* out = (float*)d_out;

  float* w_rv = (float*)d_ws;
  float* w_bc = w_rv + Cc * Kk;

  const int n = in_sizes[0] / Dd;  // 131072 pixels

  prep_kernel<<<Cc, 64, 0, stream>>>(pca_mean, comps, var, mu, w_rv, w_bc);

  const int blocks = (n + TPB - 1) / TPB;
  outlier_kernel<<<blocks, TPB, 0, stream>>>(feats, comps, cov_inv,
                                             w_rv, w_bc, out, n);
}

// Round 3
// 4112.184 us; speedup vs baseline: 2.3273x; 1.1561x over previous
//
#include <hip/hip_runtime.h>
#include <float.h>
#include <math.h>

// Problem constants (fixed by the reference)
constexpr int Cc = 19;    // classes
constexpr int Kk = 50;    // pca dim
constexpr int Dd = 256;   // feature dim

constexpr int TPB = 256;

// ---------------------------------------------------------------------------
// Prep: per (c,k) compute rv = 1/sqrt(var), bc = mean_proj*rv + mu
// ---------------------------------------------------------------------------
__global__ void prep_kernel(const float* __restrict__ pca_mean,
                            const float* __restrict__ comps,
                            const float* __restrict__ var,
                            const float* __restrict__ mu,
                            float* __restrict__ w_rv,
                            float* __restrict__ w_bc) {
  int c = blockIdx.x;
  int k = threadIdx.x;
  if (k >= Kk) return;
  const float* m  = pca_mean + (size_t)c * Dd;
  const float* cp = comps + ((size_t)(c * Kk + k)) * Dd;
  float s = 0.f;
  #pragma unroll 8
  for (int d = 0; d < Dd; ++d) s = fmaf(m[d], cp[d], s);
  float rv = 1.0f / sqrtf(var[c * Kk + k]);
  w_rv[c * Kk + k] = rv;
  w_bc[c * Kk + k] = fmaf(s, rv, mu[c * Kk + k]);
}

// ---------------------------------------------------------------------------
// Main: one pixel per thread, ZERO LDS. All class data (comps rows, cov_inv
// rows, rv/bc) is wave-uniform -> scalar (s_load) path; inner FMAs are
// v_fmac v,s,v.
//
// Round-2 lesson: bare __launch_bounds__(256) let the allocator target
// 8 waves/SIMD = 64 VGPR, forcing z[50] into AGPRs (accvgpr_read/write
// around every FMA, ~3x VALU inflation). Fix: (256,4) caps at 128 VGPR;
// live state ~75 VGPR fits cleanly. Feats staged 8 floats/step (not 16)
// to keep pressure down and leave SGPRs for s_load prefetch depth.
// ---------------------------------------------------------------------------
__global__ __launch_bounds__(TPB, 4) void outlier_kernel(
    const float* __restrict__ feats,
    const float* __restrict__ comps,
    const float* __restrict__ cov_inv,
    const float* __restrict__ w_rv,
    const float* __restrict__ w_bc,
    float* __restrict__ out, int n) {
  const int p = blockIdx.x * TPB + threadIdx.x;
  if (p >= n) return;
  const float4* __restrict__ F = (const float4*)(feats + (size_t)p * Dd);

  float dmin = FLT_MAX;

  #pragma unroll 1          // keep class body out of I$ blowup
  for (int c = 0; c < Cc; ++c) {
    const float4* __restrict__ cb =
        (const float4*)(comps + (size_t)c * Kk * Dd);   // uniform base

    // Projection: z[k] = comps[c,k,:] . feats[p,:]
    float z[Kk];
    #pragma unroll
    for (int k = 0; k < Kk; ++k) z[k] = 0.f;

    #pragma unroll 1        // 32 iters; k-loop inside fully unrolled
    for (int dc = 0; dc < Dd / 4; dc += 2) {
      // 8 floats of this pixel's feats row resident in VGPRs
      float4 fa = F[dc];
      float4 fb = F[dc + 1];
      #pragma unroll        // z[] is register-indexed: must fully unroll
      for (int k = 0; k < Kk; ++k) {
        const float4* row = cb + k * (Dd / 4) + dc;  // uniform -> s_load
        float4 r0 = row[0];
        float4 r1 = row[1];
        float t = z[k];
        t = fmaf(r0.x, fa.x, t); t = fmaf(r0.y, fa.y, t);
        t = fmaf(r0.z, fa.z, t); t = fmaf(r0.w, fa.w, t);
        t = fmaf(r1.x, fb.x, t); t = fmaf(r1.y, fb.y, t);
        t = fmaf(r1.z, fb.z, t); t = fmaf(r1.w, fb.w, t);
        z[k] = t;
      }
    }

    // v = z*rv - (mean_proj*rv + mu)   (rv/bc uniform scalar loads)
    #pragma unroll
    for (int k = 0; k < Kk; ++k) {
      float rv = w_rv[c * Kk + k];
      float bc = w_bc[c * Kk + k];
      z[k] = fmaf(z[k], rv, -bc);
    }

    // dist = v^T M v  (M rows uniform -> scalar loads)
    float dist = 0.f;
    #pragma unroll
    for (int k = 0; k < Kk; ++k) {
      const float2* row =
          (const float2*)(cov_inv + ((size_t)c * Kk + k) * Kk);  // 8B aligned
      float s = 0.f;
      #pragma unroll
      for (int l = 0; l < Kk / 2; ++l) {
        float2 m2 = row[l];
        s = fmaf(m2.x, z[2 * l], s);
        s = fmaf(m2.y, z[2 * l + 1], s);
      }
      dist = fmaf(z[k], s, dist);
    }
    dmin = fminf(dmin, dist);
  }

  out[p] = dmin;
}

extern "C" void kernel_launch(void* const* d_in, const int* in_sizes, int n_in,
                              void* d_out, int out_size, void* d_ws, size_t ws_size,
                              hipStream_t stream) {
  const float* feats    = (const float*)d_in[0];
  const float* pca_mean = (const float*)d_in[1];
  const float* comps    = (const float*)d_in[2];
  const float* var      = (const float*)d_in[3];
  const float* mu       = (const float*)d_in[4];
  const float* cov_inv  = (const float*)d_in[5];
  float* out = (float*)d_out;

  float* w_rv = (float*)d_ws;
  float* w_bc = w_rv + Cc * Kk;

  const int n = in_sizes[0] / Dd;  // 131072 pixels

  prep_kernel<<<Cc, 64, 0, stream>>>(pca_mean, comps, var, mu, w_rv, w_bc);

  const int blocks = (n + TPB - 1) / TPB;
  outlier_kernel<<<blocks, TPB, 0, stream>>>(feats, comps, cov_inv,
                                             w_rv, w_bc, out, n);
}

// Round 4
// 2959.551 us; speedup vs baseline: 3.2337x; 1.3895x over previous
//
#include <hip/hip_runtime.h>
#include <float.h>
#include <math.h>

// Problem constants (fixed by the reference)
constexpr int Cc = 19;    // classes
constexpr int Kk = 50;    // pca dim
constexpr int Dd = 256;   // feature dim

constexpr int TPB = 256;

// ---------------------------------------------------------------------------
// Prep: per (c,k) compute rv = 1/sqrt(var), bc = mean_proj*rv + mu
// ---------------------------------------------------------------------------
__global__ void prep_kernel(const float* __restrict__ pca_mean,
                            const float* __restrict__ comps,
                            const float* __restrict__ var,
                            const float* __restrict__ mu,
                            float* __restrict__ w_rv,
                            float* __restrict__ w_bc) {
  int c = blockIdx.x;
  int k = threadIdx.x;
  if (k >= Kk) return;
  const float* m  = pca_mean + (size_t)c * Dd;
  const float* cp = comps + ((size_t)(c * Kk + k)) * Dd;
  float s = 0.f;
  #pragma unroll 8
  for (int d = 0; d < Dd; ++d) s = fmaf(m[d], cp[d], s);
  float rv = 1.0f / sqrtf(var[c * Kk + k]);
  w_rv[c * Kk + k] = rv;
  w_bc[c * Kk + k] = fmaf(s, rv, mu[c * Kk + k]);
}

// ---------------------------------------------------------------------------
// Main: one pixel per thread, ZERO LDS. All class data (comps rows, cov_inv
// rows, rv/bc) is wave-uniform -> scalar (s_load) path; inner FMAs are
// v_fmac v,s,v.
//
// Round-3 lesson: the grid only supplies 2 waves/SIMD (2048 waves / 1024
// SIMDs) — occupancy is grid-limited at 25% in every configuration. But the
// allocator kept optimizing for 8 waves/SIMD, holding arch-VGPR use at
// 36-64 by placing z[50] in AGPRs; with an SGPR operand in the same FMA
// that forces accvgpr_read/write pairs => ~3.7x VALU inflation (measured:
// dur*VALUBusy = 1810us of VALU vs 486us floor). Fix: pin
// amdgpu_waves_per_eu(2,2) -> 256-VGPR budget per wave, matching what the
// grid actually delivers; z stays in plain VGPRs.
// ---------------------------------------------------------------------------
__global__ __launch_bounds__(TPB)
__attribute__((amdgpu_waves_per_eu(2, 2)))
void outlier_kernel(
    const float* __restrict__ feats,
    const float* __restrict__ comps,
    const float* __restrict__ cov_inv,
    const float* __restrict__ w_rv,
    const float* __restrict__ w_bc,
    float* __restrict__ out, int n) {
  const int p = blockIdx.x * TPB + threadIdx.x;
  if (p >= n) return;
  const float4* __restrict__ F = (const float4*)(feats + (size_t)p * Dd);

  float dmin = FLT_MAX;

  #pragma unroll 1          // keep class body out of I$ blowup
  for (int c = 0; c < Cc; ++c) {
    const float4* __restrict__ cb =
        (const float4*)(comps + (size_t)c * Kk * Dd);   // uniform base

    // Projection: z[k] = comps[c,k,:] . feats[p,:]
    float z[Kk];
    #pragma unroll
    for (int k = 0; k < Kk; ++k) z[k] = 0.f;

    #pragma unroll 1        // 16 iters; k-loop inside fully unrolled
    for (int dc = 0; dc < Dd / 4; dc += 4) {
      // 16 floats of this pixel's feats row resident in VGPRs
      float4 fa = F[dc];
      float4 fb = F[dc + 1];
      float4 fc = F[dc + 2];
      float4 fd = F[dc + 3];
      #pragma unroll        // z[] is register-indexed: must fully unroll
      for (int k = 0; k < Kk; ++k) {
        const float4* row = cb + k * (Dd / 4) + dc;  // uniform -> s_load
        float4 r0 = row[0];
        float4 r1 = row[1];
        float4 r2 = row[2];
        float4 r3 = row[3];
        float t = z[k];
        t = fmaf(r0.x, fa.x, t); t = fmaf(r0.y, fa.y, t);
        t = fmaf(r0.z, fa.z, t); t = fmaf(r0.w, fa.w, t);
        t = fmaf(r1.x, fb.x, t); t = fmaf(r1.y, fb.y, t);
        t = fmaf(r1.z, fb.z, t); t = fmaf(r1.w, fb.w, t);
        t = fmaf(r2.x, fc.x, t); t = fmaf(r2.y, fc.y, t);
        t = fmaf(r2.z, fc.z, t); t = fmaf(r2.w, fc.w, t);
        t = fmaf(r3.x, fd.x, t); t = fmaf(r3.y, fd.y, t);
        t = fmaf(r3.z, fd.z, t); t = fmaf(r3.w, fd.w, t);
        z[k] = t;
      }
    }

    // v = z*rv - (mean_proj*rv + mu)   (rv/bc uniform scalar loads)
    #pragma unroll
    for (int k = 0; k < Kk; ++k) {
      float rv = w_rv[c * Kk + k];
      float bc = w_bc[c * Kk + k];
      z[k] = fmaf(z[k], rv, -bc);
    }

    // dist = v^T M v  (M rows uniform -> scalar loads)
    float dist = 0.f;
    #pragma unroll
    for (int k = 0; k < Kk; ++k) {
      const float2* row =
          (const float2*)(cov_inv + ((size_t)c * Kk + k) * Kk);  // 8B aligned
      float s = 0.f;
      #pragma unroll
      for (int l = 0; l < Kk / 2; ++l) {
        float2 m2 = row[l];
        s = fmaf(m2.x, z[2 * l], s);
        s = fmaf(m2.y, z[2 * l + 1], s);
      }
      dist = fmaf(z[k], s, dist);
    }
    dmin = fminf(dmin, dist);
  }

  out[p] = dmin;
}

extern "C" void kernel_launch(void* const* d_in, const int* in_sizes, int n_in,
                              void* d_out, int out_size, void* d_ws, size_t ws_size,
                              hipStream_t stream) {
  const float* feats    = (const float*)d_in[0];
  const float* pca_mean = (const float*)d_in[1];
  const float* comps    = (const float*)d_in[2];
  const float* var      = (const float*)d_in[3];
  const float* mu       = (const float*)d_in[4];
  const float* cov_inv  = (const float*)d_in[5];
  float* out = (float*)d_out;

  float* w_rv = (float*)d_ws;
  float* w_bc = w_rv + Cc * Kk;

  const int n = in_sizes[0] / Dd;  // 131072 pixels

  prep_kernel<<<Cc, 64, 0, stream>>>(pca_mean, comps, var, mu, w_rv, w_bc);

  const int blocks = (n + TPB - 1) / TPB;
  outlier_kernel<<<blocks, TPB, 0, stream>>>(feats, comps, cov_inv,
                                             w_rv, w_bc, out, n);
}

// Round 5
// 1550.692 us; speedup vs baseline: 6.1716x; 1.9085x over previous
//
#include <hip/hip_runtime.h>
#include <float.h>
#include <math.h>

// Problem constants (fixed by the reference)
constexpr int Cc = 19;    // classes
constexpr int Kk = 50;    // pca dim
constexpr int Dd = 256;   // feature dim

constexpr int TPB = 256;

// ---------------------------------------------------------------------------
// Prep: per (c,k) compute rv = 1/sqrt(var), bc = mean_proj*rv + mu
// ---------------------------------------------------------------------------
__global__ void prep_kernel(const float* __restrict__ pca_mean,
                            const float* __restrict__ comps,
                            const float* __restrict__ var,
                            const float* __restrict__ mu,
                            float* __restrict__ w_rv,
                            float* __restrict__ w_bc) {
  int c = blockIdx.x;
  int k = threadIdx.x;
  if (k >= Kk) return;
  const float* m  = pca_mean + (size_t)c * Dd;
  const float* cp = comps + ((size_t)(c * Kk + k)) * Dd;
  float s = 0.f;
  #pragma unroll 8
  for (int d = 0; d < Dd; ++d) s = fmaf(m[d], cp[d], s);
  float rv = 1.0f / sqrtf(var[c * Kk + k]);
  w_rv[c * Kk + k] = rv;
  w_bc[c * Kk + k] = fmaf(s, rv, mu[c * Kk + k]);
}

// ---------------------------------------------------------------------------
// Init output to +FLT_MAX so per-class blocks can atomicMin into it.
// ---------------------------------------------------------------------------
__global__ void init_kernel(float* __restrict__ out, int n) {
  int i = blockIdx.x * blockDim.x + threadIdx.x;
  if (i < n) out[i] = FLT_MAX;
}

// ---------------------------------------------------------------------------
// Main: one pixel per thread, ONE CLASS PER BLOCK, zero LDS. Class data
// (comps rows, cov_inv rows, rv/bc) is wave-uniform -> scalar s_load path;
// inner FMAs are single v_fmac v,s,v.
//
// Round-4 post-mortem: per-wave VALU work is already at the 486us floor
// (dur*VALUBusy = 533us) — the 82% stall is s_load lgkmcnt(0) drains
// covered by only 2 waves/SIMD, because the grid supplied 2048 waves and
// waves_per_eu(2,2) pinned residency. Fix TLP, not the instruction stream:
// split classes across blocks (grid x19 = 38912 waves), combine via
// atomicMin on float bits (dist >= 0 since cov_inv SPD => uint order ==
// float order). waves_per_eu(4,4): 128-VGPR budget > 88 demand (no AGPR
// relapse), 4 waves/SIMD resident. Tile-major block order: co-resident
// blocks share feats rows (L1 hits) while scalar streams differ.
// ---------------------------------------------------------------------------
__global__ __launch_bounds__(TPB)
__attribute__((amdgpu_waves_per_eu(4, 4)))
void outlier_kernel(
    const float* __restrict__ feats,
    const float* __restrict__ comps,
    const float* __restrict__ cov_inv,
    const float* __restrict__ w_rv,
    const float* __restrict__ w_bc,
    float* __restrict__ out, int n) {
  const int tile = blockIdx.x / Cc;   // consecutive bids = same pixel tile
  const int c    = blockIdx.x % Cc;   // ... all 19 classes
  const int p = tile * TPB + threadIdx.x;
  if (p >= n) return;
  const float4* __restrict__ F = (const float4*)(feats + (size_t)p * Dd);
  const float4* __restrict__ cb =
      (const float4*)(comps + (size_t)c * Kk * Dd);   // uniform base

  // Projection: z[k] = comps[c,k,:] . feats[p,:]
  float z[Kk];
  #pragma unroll
  for (int k = 0; k < Kk; ++k) z[k] = 0.f;

  #pragma unroll 1          // 16 iters; k-loop inside fully unrolled
  for (int dc = 0; dc < Dd / 4; dc += 4) {
    // 16 floats of this pixel's feats row resident in VGPRs
    float4 fa = F[dc];
    float4 fb = F[dc + 1];
    float4 fc = F[dc + 2];
    float4 fd = F[dc + 3];
    #pragma unroll          // z[] is register-indexed: must fully unroll
    for (int k = 0; k < Kk; ++k) {
      const float4* row = cb + k * (Dd / 4) + dc;  // uniform, 64B -> s_load
      float4 r0 = row[0];
      float4 r1 = row[1];
      float4 r2 = row[2];
      float4 r3 = row[3];
      float t = z[k];
      t = fmaf(r0.x, fa.x, t); t = fmaf(r0.y, fa.y, t);
      t = fmaf(r0.z, fa.z, t); t = fmaf(r0.w, fa.w, t);
      t = fmaf(r1.x, fb.x, t); t = fmaf(r1.y, fb.y, t);
      t = fmaf(r1.z, fb.z, t); t = fmaf(r1.w, fb.w, t);
      t = fmaf(r2.x, fc.x, t); t = fmaf(r2.y, fc.y, t);
      t = fmaf(r2.z, fc.z, t); t = fmaf(r2.w, fc.w, t);
      t = fmaf(r3.x, fd.x, t); t = fmaf(r3.y, fd.y, t);
      t = fmaf(r3.z, fd.z, t); t = fmaf(r3.w, fd.w, t);
      z[k] = t;
    }
  }

  // v = z*rv - (mean_proj*rv + mu)   (rv/bc uniform scalar loads)
  #pragma unroll
  for (int k = 0; k < Kk; ++k) {
    float rv = w_rv[c * Kk + k];
    float bc = w_bc[c * Kk + k];
    z[k] = fmaf(z[k], rv, -bc);
  }

  // dist = v^T M v  (M rows uniform -> scalar loads)
  float dist = 0.f;
  #pragma unroll
  for (int k = 0; k < Kk; ++k) {
    const float2* row =
        (const float2*)(cov_inv + ((size_t)c * Kk + k) * Kk);  // 8B aligned
    float s = 0.f;
    #pragma unroll
    for (int l = 0; l < Kk / 2; ++l) {
      float2 m2 = row[l];
      s = fmaf(m2.x, z[2 * l], s);
      s = fmaf(m2.y, z[2 * l + 1], s);
    }
    dist = fmaf(z[k], s, dist);
  }

  // Combine classes: dist >= 0, so uint compare == float compare.
  atomicMin((unsigned*)out + p, __float_as_uint(dist));
}

extern "C" void kernel_launch(void* const* d_in, const int* in_sizes, int n_in,
                              void* d_out, int out_size, void* d_ws, size_t ws_size,
                              hipStream_t stream) {
  const float* feats    = (const float*)d_in[0];
  const float* pca_mean = (const float*)d_in[1];
  const float* comps    = (const float*)d_in[2];
  const float* var      = (const float*)d_in[3];
  const float* mu       = (const float*)d_in[4];
  const float* cov_inv  = (const float*)d_in[5];
  float* out = (float*)d_out;

  float* w_rv = (float*)d_ws;
  float* w_bc = w_rv + Cc * Kk;

  const int n = in_sizes[0] / Dd;  // 131072 pixels

  prep_kernel<<<Cc, 64, 0, stream>>>(pca_mean, comps, var, mu, w_rv, w_bc);
  init_kernel<<<(n + TPB - 1) / TPB, TPB, 0, stream>>>(out, n);

  const int tiles = (n + TPB - 1) / TPB;  // 512
  outlier_kernel<<<tiles * Cc, TPB, 0, stream>>>(feats, comps, cov_inv,
                                                 w_rv, w_bc, out, n);
}

// Round 6
// 542.470 us; speedup vs baseline: 17.6419x; 2.8586x over previous
//
#include <hip/hip_runtime.h>
#include <float.h>
#include <math.h>

// Problem constants (fixed by the reference)
constexpr int Cc = 19;    // classes
constexpr int Kk = 50;    // pca dim
constexpr int Dd = 256;   // feature dim

constexpr int NCOL = 64;          // padded cols per class (50 -> 64)
constexpr int CPAD = 20;          // classes incl 1 dummy pad class
constexpr int ROWS = CPAD * NCOL; // 1280 rows of the stacked B matrix
constexpr int MT   = 128;         // pixels per block
constexpr int THR  = 512;         // 8 waves

typedef float  f32x4  __attribute__((ext_vector_type(4)));
typedef short  bf16x8 __attribute__((ext_vector_type(8)));

__device__ __forceinline__ unsigned short f2bf(float x) {
  unsigned u = __float_as_uint(x);
  unsigned r = 0x7FFFu + ((u >> 16) & 1u);   // round-to-nearest-even
  return (unsigned short)((u + r) >> 16);
}
__device__ __forceinline__ float bf2f(unsigned short h) {
  return __uint_as_float(((unsigned)h) << 16);
}

// ---------------------------------------------------------------------------
// Prep 1: per (c,k) rv = 1/sqrt(var), bc = mean_proj*rv + mu
// ---------------------------------------------------------------------------
__global__ void prep_kernel(const float* __restrict__ pca_mean,
                            const float* __restrict__ comps,
                            const float* __restrict__ var,
                            const float* __restrict__ mu,
                            float* __restrict__ w_rv,
                            float* __restrict__ w_bc) {
  int c = blockIdx.x;
  int k = threadIdx.x;
  if (k >= Kk) return;
  const float* m  = pca_mean + (size_t)c * Dd;
  const float* cp = comps + ((size_t)(c * Kk + k)) * Dd;
  float s = 0.f;
  #pragma unroll 8
  for (int d = 0; d < Dd; ++d) s = fmaf(m[d], cp[d], s);
  float rv = 1.0f / sqrtf(var[c * Kk + k]);
  w_rv[c * Kk + k] = rv;
  w_bc[c * Kk + k] = fmaf(s, rv, mu[c * Kk + k]);
}

// ---------------------------------------------------------------------------
// Prep 2: Cholesky cov_inv[c] = L L^T (right-looking, in LDS), plus
// g[c][j] = sum_{k>=j} L[k][j]*bc[c][k]  (g = L^T bc), g=0 for j>=50.
// dist = v^T M v = ||L^T v||^2.
// ---------------------------------------------------------------------------
__global__ void chol_kernel(const float* __restrict__ cov_inv,
                            const float* __restrict__ w_bc,
                            float* __restrict__ Lmat,
                            float* __restrict__ g) {
  __shared__ float M[Kk * Kk];
  const int c = blockIdx.x, t = threadIdx.x;
  for (int i = t; i < Kk * Kk; i += 64) M[i] = cov_inv[(size_t)c * Kk * Kk + i];
  __syncthreads();
  for (int j = 0; j < Kk; ++j) {
    if (t == 0) M[j * Kk + j] = sqrtf(M[j * Kk + j]);
    __syncthreads();
    float dj = M[j * Kk + j];
    for (int i = j + 1 + t; i < Kk; i += 64) M[i * Kk + j] /= dj;
    __syncthreads();
    for (int i = j + 1 + t; i < Kk; i += 64) {
      float mij = M[i * Kk + j];
      for (int l = j + 1; l <= i; ++l) M[i * Kk + l] -= mij * M[l * Kk + j];
    }
    __syncthreads();
  }
  for (int i = t; i < Kk * Kk; i += 64) Lmat[(size_t)c * Kk * Kk + i] = M[i];
  // g (t indexes padded col j)
  float s = 0.f;
  if (t < Kk) {
    for (int k = t; k < Kk; ++k) s = fmaf(M[k * Kk + t], w_bc[c * Kk + k], s);
  }
  if (t < NCOL) g[c * NCOL + t] = s;
}

// ---------------------------------------------------------------------------
// Prep 3: stacked split-bf16 B matrix.
// Row r = c*64+j (c<19, j<50): B[j][d] = sum_{k>=j} L[k][j]*rv[k]*comps[c][k][d]
// stored as bf16 hi at Bs[r][d], residual lo at Bs[r][256+d]. Pad rows zero.
// Pad class (c==19): g = 1e18 so its dist is huge and never wins the min.
// ---------------------------------------------------------------------------
__global__ void prepB_kernel(const float* __restrict__ comps,
                             const float* __restrict__ w_rv,
                             const float* __restrict__ Lmat,
                             float* __restrict__ g,
                             unsigned short* __restrict__ Bs) {
  const int r = blockIdx.x;          // 0..1279
  const int c = r >> 6, j = r & 63;
  const int t = threadIdx.x;
  if (c >= Cc || j >= Kk) {
    for (int d = t; d < 2 * Dd; d += 64) Bs[(size_t)r * 512 + d] = 0;
    if (c >= Cc && t == 0) g[r] = 1e18f;
    return;
  }
  for (int d = t; d < Dd; d += 64) {
    float s = 0.f;
    for (int k = j; k < Kk; ++k)
      s = fmaf(Lmat[(size_t)c * Kk * Kk + k * Kk + j] * w_rv[c * Kk + k],
               comps[((size_t)c * Kk + k) * Dd + d], s);
    unsigned short hi = f2bf(s);
    Bs[(size_t)r * 512 + d]       = hi;
    Bs[(size_t)r * 512 + Dd + d]  = f2bf(s - bf2f(hi));
  }
}

// ---------------------------------------------------------------------------
// Main: split-bf16 MFMA GEMM  W = F * Bs^T  fused with the distance epilogue.
// dist[p][c] = sum_j (W[p][c*64+j] - g[c][j])^2 ; out[p] = min_c dist.
//
// Split-bf16 (hi+lo) via stacked K=768: seg0 A_hi*B_hi, seg1 A_lo*B_hi,
// seg2 A_hi*B_lo (lo*lo dropped, ~2^-18 relative -> dist err ~1e-3).
//
// Block: 128 px, 512 thr (8 waves = 4 row-quarters x 2 classes-of-pair).
// A tile (feats hi|lo) in swizzled LDS (128KB), staged once, reused for all
// 20 classes. B streamed per 32-k step, double-buffered (16KB), T14 split
// (issue global load early, ds_write after MFMA). Classes processed in 10
// pairs; per-pair epilogue is per-lane (Cholesky fold), 16-lane shuffle
// row-sum, per-wave running min, final cross-wave LDS atomicMin.
// MFMA fragment layouts (m89/m91-verified): A/B lane l: row=l&15,
// k=(l>>4)*8+j ; C/D: col=lane&15, row=(lane>>4)*4+reg.
// ---------------------------------------------------------------------------
__global__ __launch_bounds__(THR)
__attribute__((amdgpu_waves_per_eu(2, 2)))
void mfma_kernel(const float* __restrict__ feats,
                 const unsigned short* __restrict__ Bs,
                 const float* __restrict__ g,
                 float* __restrict__ out) {
  __shared__ unsigned short sA[MT * 512];          // 131072 B, xor-swizzled
  __shared__ unsigned short sB[2][2][NCOL * 32];   // 16384 B, xor-swizzled
  __shared__ float    sg[2][NCOL];
  __shared__ unsigned sOut[MT];

  const int tid  = threadIdx.x;
  const int lane = tid & 63;
  const int wid  = tid >> 6;
  const int mw   = wid >> 1;    // row-quarter: px rows [mw*32, mw*32+32)
  const int clr  = wid & 1;     // which class of the current pair
  const size_t pxbase = (size_t)blockIdx.x * MT;

  if (tid < MT) sOut[tid] = 0x7F7FFFFFu;   // FLT_MAX bits

  // ---- Stage A: fp32 feats -> bf16 hi (k 0..255) | lo (k 256..511), swizzled
  {
    const int px = tid >> 2;
    const int db = (tid & 3) * 64;
    const float4* src = (const float4*)(feats + (pxbase + px) * Dd + db);
    char* base = (char*)sA;
    #pragma unroll 4
    for (int i = 0; i < 16; ++i) {
      float4 f = src[i];
      int k = db + i * 4;
      unsigned short h0 = f2bf(f.x), h1 = f2bf(f.y), h2 = f2bf(f.z), h3 = f2bf(f.w);
      unsigned short l0 = f2bf(f.x - bf2f(h0)), l1 = f2bf(f.y - bf2f(h1));
      unsigned short l2 = f2bf(f.z - bf2f(h2)), l3 = f2bf(f.w - bf2f(h3));
      uint2 hv, lv;
      hv.x = (unsigned)h0 | ((unsigned)h1 << 16); hv.y = (unsigned)h2 | ((unsigned)h3 << 16);
      lv.x = (unsigned)l0 | ((unsigned)l1 << 16); lv.y = (unsigned)l2 | ((unsigned)l3 << 16);
      unsigned hadr = (unsigned)(px * 1024 + k * 2)            ^ ((px & 7) << 4);
      unsigned ladr = (unsigned)(px * 1024 + (Dd + k) * 2)     ^ ((px & 7) << 4);
      *(uint2*)(base + hadr) = hv;
      *(uint2*)(base + ladr) = lv;
    }
  }

  float dmin[2][4];
  #pragma unroll
  for (int mf = 0; mf < 2; ++mf)
    #pragma unroll
    for (int r = 0; r < 4; ++r) dmin[mf][r] = FLT_MAX;

  // B staging indices (per thread: 16 bytes of one chunk)
  const int s_cl  = tid >> 8;          // 0..1
  const int s_col = (tid >> 2) & 63;   // 0..63
  const int s_kq  = (tid & 3) * 8;     // 0,8,16,24
  const unsigned s_ldsoff =
      (unsigned)((s_cl * 4096) +
                 (((s_col * 64 + s_kq * 2)) ^ (((s_col >> 1) & 3) << 4)));

  // A-frag read addresses (per wave/lane, varying only in k per step)
  const int a_row0 = mw * 32 + (lane & 15);        // mf=0
  const int a_kq   = (lane >> 4) * 8;

  #pragma unroll 1
  for (int cp = 0; cp < CPAD / 2; ++cp) {
    const int c0 = cp * 2;
    __syncthreads();   // prev pair epilogue done before sg / sB reuse
    if (tid < 2 * NCOL) sg[tid >> 6][tid & 63] = g[(c0 + (tid >> 6)) * NCOL + (tid & 63)];

    // stage kstep 0 into buf 0
    {
      const unsigned short* gp = Bs + ((size_t)(c0 + s_cl) * NCOL + s_col) * 512 + s_kq;
      int4 v = *(const int4*)gp;
      *(int4*)((char*)sB + s_ldsoff) = v;   // buf 0 at offset 0
    }
    __syncthreads();

    f32x4 acc[2][4];
    #pragma unroll
    for (int mf = 0; mf < 2; ++mf)
      #pragma unroll
      for (int nf = 0; nf < 4; ++nf) acc[mf][nf] = (f32x4)0.f;

    #pragma unroll 2
    for (int t = 0; t < 24; ++t) {
      const int buf = t & 1;
      // ---- T14: issue next chunk's global load early
      int4 pre;
      if (t < 23) {
        const int tn   = t + 1;
        const int segn = tn >> 3;
        const int bko  = ((segn == 2) ? 256 : 0) + (tn & 7) * 32;
        const unsigned short* gp =
            Bs + ((size_t)(c0 + s_cl) * NCOL + s_col) * 512 + bko + s_kq;
        pre = *(const int4*)gp;
      }
      // ---- compute kstep t from buf
      const int seg  = t >> 3;
      const int a_k  = ((seg == 1) ? 256 : 0) + (t & 7) * 32 + a_kq;
      unsigned a0adr = (unsigned)(a_row0 * 1024 + a_k * 2)          ^ ((a_row0 & 7) << 4);
      const int a_row1 = a_row0 + 16;
      unsigned a1adr = (unsigned)(a_row1 * 1024 + a_k * 2)          ^ ((a_row1 & 7) << 4);
      bf16x8 a0 = *(const bf16x8*)((const char*)sA + a0adr);
      bf16x8 a1 = *(const bf16x8*)((const char*)sA + a1adr);
      const unsigned bbase = (unsigned)((buf * 2 + clr) * 4096);
      #pragma unroll
      for (int nf = 0; nf < 4; ++nf) {
        const int col = nf * 16 + (lane & 15);
        unsigned badr = bbase +
            ((unsigned)(col * 64 + a_kq * 2) ^ (((col >> 1) & 3) << 4));
        bf16x8 b = *(const bf16x8*)((const char*)sB + badr);
        acc[0][nf] = __builtin_amdgcn_mfma_f32_16x16x32_bf16(a0, b, acc[0][nf], 0, 0, 0);
        acc[1][nf] = __builtin_amdgcn_mfma_f32_16x16x32_bf16(a1, b, acc[1][nf], 0, 0, 0);
      }
      // ---- T14: write next chunk to the other buffer after compute
      if (t < 23) {
        *(int4*)((char*)sB + (unsigned)(((buf ^ 1) * 2) * 4096) + s_ldsoff) = pre;
      }
      __syncthreads();
    }

    // ---- epilogue for this pair's class (c0+clr)
    const int colb = lane & 15;
    #pragma unroll
    for (int mf = 0; mf < 2; ++mf) {
      float ps0 = 0.f, ps1 = 0.f, ps2 = 0.f, ps3 = 0.f;
      #pragma unroll
      for (int nf = 0; nf < 4; ++nf) {
        float gv = sg[clr][nf * 16 + colb];
        float t0 = acc[mf][nf][0] - gv; ps0 = fmaf(t0, t0, ps0);
        float t1 = acc[mf][nf][1] - gv; ps1 = fmaf(t1, t1, ps1);
        float t2 = acc[mf][nf][2] - gv; ps2 = fmaf(t2, t2, ps2);
        float t3 = acc[mf][nf][3] - gv; ps3 = fmaf(t3, t3, ps3);
      }
      #pragma unroll
      for (int off = 1; off < 16; off <<= 1) {
        ps0 += __shfl_xor(ps0, off);
        ps1 += __shfl_xor(ps1, off);
        ps2 += __shfl_xor(ps2, off);
        ps3 += __shfl_xor(ps3, off);
      }
      dmin[mf][0] = fminf(dmin[mf][0], ps0);
      dmin[mf][1] = fminf(dmin[mf][1], ps1);
      dmin[mf][2] = fminf(dmin[mf][2], ps2);
      dmin[mf][3] = fminf(dmin[mf][3], ps3);
    }
  }

  // ---- combine the two class-role waves per row-quarter, then write
  if ((lane & 15) == 0) {
    #pragma unroll
    for (int mf = 0; mf < 2; ++mf)
      #pragma unroll
      for (int r = 0; r < 4; ++r) {
        int lpx = mw * 32 + mf * 16 + (lane >> 4) * 4 + r;
        atomicMin(&sOut[lpx], __float_as_uint(dmin[mf][r]));
      }
  }
  __syncthreads();
  if (tid < MT) out[pxbase + tid] = __uint_as_float(sOut[tid]);
}

extern "C" void kernel_launch(void* const* d_in, const int* in_sizes, int n_in,
                              void* d_out, int out_size, void* d_ws, size_t ws_size,
                              hipStream_t stream) {
  const float* feats    = (const float*)d_in[0];
  const float* pca_mean = (const float*)d_in[1];
  const float* comps    = (const float*)d_in[2];
  const float* var      = (const float*)d_in[3];
  const float* mu       = (const float*)d_in[4];
  const float* cov_inv  = (const float*)d_in[5];
  float* out = (float*)d_out;

  // workspace layout (floats): rv[950] bc[950] L[19*2500] g[1280] Bs(bf16)[1280*512]
  float* w_rv = (float*)d_ws;
  float* w_bc = w_rv + Cc * Kk;
  float* Lmat = w_bc + Cc * Kk;
  float* gv   = Lmat + Cc * Kk * Kk;
  unsigned short* Bs = (unsigned short*)(gv + ROWS);
  // total ~1.6 MB of workspace

  const int n = in_sizes[0] / Dd;  // 131072 pixels

  prep_kernel<<<Cc, 64, 0, stream>>>(pca_mean, comps, var, mu, w_rv, w_bc);
  chol_kernel<<<Cc, 64, 0, stream>>>(cov_inv, w_bc, Lmat, gv);
  prepB_kernel<<<ROWS, 64, 0, stream>>>(comps, w_rv, Lmat, gv, Bs);
  mfma_kernel<<<n / MT, THR, 0, stream>>>(feats, Bs, gv, out);
}

// Round 7
// 461.665 us; speedup vs baseline: 20.7297x; 1.1750x over previous
//
#include <hip/hip_runtime.h>
#include <float.h>
#include <math.h>

// Problem constants (fixed by the reference)
constexpr int Cc = 19;    // classes
constexpr int Kk = 50;    // pca dim
constexpr int Dd = 256;   // feature dim

constexpr int NCOL = 64;          // padded cols per class (50 -> 64)
constexpr int CPAD = 20;          // classes incl 1 dummy pad class
constexpr int ROWS = CPAD * NCOL; // 1280 rows of the stacked B matrix
constexpr int MT   = 128;         // pixels per block
constexpr int THR  = 512;         // 8 waves

typedef float  f32x4  __attribute__((ext_vector_type(4)));
typedef short  bf16x8 __attribute__((ext_vector_type(8)));

__device__ __forceinline__ unsigned short f2bf(float x) {
  unsigned u = __float_as_uint(x);
  unsigned r = 0x7FFFu + ((u >> 16) & 1u);   // round-to-nearest-even
  return (unsigned short)((u + r) >> 16);
}
__device__ __forceinline__ float bf2f(unsigned short h) {
  return __uint_as_float(((unsigned)h) << 16);
}

// ---------------------------------------------------------------------------
// Prep 1: per (c,k) rv = 1/sqrt(var), bc = mean_proj*rv + mu
// ---------------------------------------------------------------------------
__global__ void prep_kernel(const float* __restrict__ pca_mean,
                            const float* __restrict__ comps,
                            const float* __restrict__ var,
                            const float* __restrict__ mu,
                            float* __restrict__ w_rv,
                            float* __restrict__ w_bc) {
  int c = blockIdx.x;
  int k = threadIdx.x;
  if (k >= Kk) return;
  const float* m  = pca_mean + (size_t)c * Dd;
  const float* cp = comps + ((size_t)(c * Kk + k)) * Dd;
  float s = 0.f;
  #pragma unroll 8
  for (int d = 0; d < Dd; ++d) s = fmaf(m[d], cp[d], s);
  float rv = 1.0f / sqrtf(var[c * Kk + k]);
  w_rv[c * Kk + k] = rv;
  w_bc[c * Kk + k] = fmaf(s, rv, mu[c * Kk + k]);
}

// ---------------------------------------------------------------------------
// Prep 2: Cholesky cov_inv[c] = L L^T (in LDS), plus g = L^T bc (0-padded).
// dist = v^T M v = ||L^T v||^2.
// ---------------------------------------------------------------------------
__global__ void chol_kernel(const float* __restrict__ cov_inv,
                            const float* __restrict__ w_bc,
                            float* __restrict__ Lmat,
                            float* __restrict__ g) {
  __shared__ float M[Kk * Kk];
  const int c = blockIdx.x, t = threadIdx.x;
  for (int i = t; i < Kk * Kk; i += 64) M[i] = cov_inv[(size_t)c * Kk * Kk + i];
  __syncthreads();
  for (int j = 0; j < Kk; ++j) {
    if (t == 0) M[j * Kk + j] = sqrtf(M[j * Kk + j]);
    __syncthreads();
    float dj = M[j * Kk + j];
    for (int i = j + 1 + t; i < Kk; i += 64) M[i * Kk + j] /= dj;
    __syncthreads();
    for (int i = j + 1 + t; i < Kk; i += 64) {
      float mij = M[i * Kk + j];
      for (int l = j + 1; l <= i; ++l) M[i * Kk + l] -= mij * M[l * Kk + j];
    }
    __syncthreads();
  }
  for (int i = t; i < Kk * Kk; i += 64) Lmat[(size_t)c * Kk * Kk + i] = M[i];
  float s = 0.f;
  if (t < Kk) {
    for (int k = t; k < Kk; ++k) s = fmaf(M[k * Kk + t], w_bc[c * Kk + k], s);
  }
  if (t < NCOL) g[c * NCOL + t] = s;
}

// ---------------------------------------------------------------------------
// Prep 3: B in FRAGMENT-ORDER global layout, split-bf16.
// B[c][j][d] = sum_{k>=j} L[k][j]*rv[k]*comps[c][k][d]; hi at K=d (chunks
// 0..7), residual lo at K=256+d (chunks 8..15). Chunk layout per (c,t):
// [col 0..63][kq 0..3][8 bf16] = 4096 B, so one wave frag-load = one
// contiguous 1024 B segment (coalesced, L2-resident).
// Pad class c==19: B=0, g=1e18 (never wins the min).
// ---------------------------------------------------------------------------
__global__ void prepB_kernel(const float* __restrict__ comps,
                             const float* __restrict__ w_rv,
                             const float* __restrict__ Lmat,
                             float* __restrict__ g,
                             unsigned short* __restrict__ Bs) {
  const int r = blockIdx.x;          // 0..1279
  const int c = r >> 6, j = r & 63;
  const int d = threadIdx.x;         // 0..255
  const unsigned hi_idx =
      (unsigned)(c * 16 + (d >> 5)) * 2048u + (unsigned)j * 32u + (unsigned)(d & 31);
  const unsigned lo_idx = hi_idx + 8u * 2048u;   // chunks 8..15
  if (c >= Cc || j >= Kk) {
    Bs[hi_idx] = 0; Bs[lo_idx] = 0;
    if (c >= Cc && d == 0) g[r] = 1e18f;
    return;
  }
  float s = 0.f;
  for (int k = j; k < Kk; ++k)
    s = fmaf(Lmat[(size_t)c * Kk * Kk + k * Kk + j] * w_rv[c * Kk + k],
             comps[((size_t)c * Kk + k) * Dd + d], s);
  unsigned short hi = f2bf(s);
  Bs[hi_idx] = hi;
  Bs[lo_idx] = f2bf(s - bf2f(hi));
}

// ---------------------------------------------------------------------------
// Main: split-bf16 MFMA GEMM with B streamed from L2 into REGISTERS.
// No __syncthreads in the k-loop: A (feats hi|lo bf16) is staged once in
// swizzled LDS (128 KB, read-only afterwards); B frags are per-wave
// global_load_dwordx4 from the fragment-ordered Bs (1.25 MB, L2-resident),
// 1-chunk register prefetch covers L2 latency. 8 waves = 2 row-halves
// (64 px, 4 mf) x 4 col-groups (32 cols, 2 nf; groups 0-1 = class c0,
// 2-3 = c1). Per B-chunk: A_hi and A_lo passes (16 MFMA per B load).
// Epilogue per pair: per-lane square-sums, 16-lane butterfly, LDS
// atomicAdd across the two col-group waves, running per-row min.
// ---------------------------------------------------------------------------
__global__ __launch_bounds__(THR)
__attribute__((amdgpu_waves_per_eu(2, 2)))
void mfma_kernel(const float* __restrict__ feats,
                 const unsigned short* __restrict__ Bs,
                 const float* __restrict__ g,
                 float* __restrict__ out) {
  __shared__ unsigned short sA[MT * 512];   // 131072 B, xor-swizzled
  __shared__ float sP[MT][2];
  __shared__ float sMin[MT];

  const int tid  = threadIdx.x;
  const int lane = tid & 63;
  const int wid  = tid >> 6;
  const int mh   = wid >> 2;          // 0..1 : rows [mh*64, +64)
  const int ng   = wid & 3;           // 0..3 : class ng>>1, colgrp (ng&1)*32
  const int clof   = ng >> 1;
  const int colgrp = (ng & 1) * 32;
  const int l15 = lane & 15;
  const int lk  = (lane >> 4) * 8;
  const size_t pxbase = (size_t)blockIdx.x * MT;

  if (tid < MT) { sMin[tid] = FLT_MAX; sP[tid][0] = 0.f; sP[tid][1] = 0.f; }

  // ---- Stage A: fp32 feats -> bf16 hi (elems 0..255) | lo (256..511)
  {
    const int px = tid >> 2;
    const int db = (tid & 3) * 64;
    const float4* src = (const float4*)(feats + (pxbase + px) * Dd + db);
    char* base = (char*)sA;
    #pragma unroll 4
    for (int i = 0; i < 16; ++i) {
      float4 f = src[i];
      int k = db + i * 4;
      unsigned short h0 = f2bf(f.x), h1 = f2bf(f.y), h2 = f2bf(f.z), h3 = f2bf(f.w);
      unsigned short l0 = f2bf(f.x - bf2f(h0)), l1 = f2bf(f.y - bf2f(h1));
      unsigned short l2 = f2bf(f.z - bf2f(h2)), l3 = f2bf(f.w - bf2f(h3));
      uint2 hv, lv;
      hv.x = (unsigned)h0 | ((unsigned)h1 << 16); hv.y = (unsigned)h2 | ((unsigned)h3 << 16);
      lv.x = (unsigned)l0 | ((unsigned)l1 << 16); lv.y = (unsigned)l2 | ((unsigned)l3 << 16);
      unsigned hadr = (unsigned)(px * 1024 + k * 2)         ^ ((px & 7) << 4);
      unsigned ladr = (unsigned)(px * 1024 + (256 + k) * 2) ^ ((px & 7) << 4);
      *(uint2*)(base + hadr) = hv;
      *(uint2*)(base + ladr) = lv;
    }
  }
  __syncthreads();

  // A-frag address components (swizzle XOR applied after row+k sum)
  unsigned rowb[4], swr[4];
  #pragma unroll
  for (int mf = 0; mf < 4; ++mf) {
    int row = mh * 64 + mf * 16 + l15;
    rowb[mf] = (unsigned)(row * 1024);
    swr[mf]  = (unsigned)((row & 7) << 4);
  }
  const char* sAc = (const char*)sA;

  #pragma unroll 1
  for (int cp = 0; cp < CPAD / 2; ++cp) {
    const int cl = cp * 2 + clof;
    const float gv0 = g[cl * NCOL + colgrp + l15];
    const float gv1 = g[cl * NCOL + colgrp + 16 + l15];
    const unsigned short* Bb = Bs + (size_t)cl * (16 * 2048);
    const unsigned be0 = (unsigned)((colgrp + l15) * 32 + lk);
    const unsigned be1 = be0 + 512;   // +16 cols

    f32x4 acc[4][2];
    #pragma unroll
    for (int mf = 0; mf < 4; ++mf) { acc[mf][0] = (f32x4)0.f; acc[mf][1] = (f32x4)0.f; }

    bf16x8 b0 = *(const bf16x8*)(Bb + be0);
    bf16x8 b1 = *(const bf16x8*)(Bb + be1);

    // ---- phase A: B_hi chunks 0..7; A_hi then A_lo (16 MFMA per B load)
    #pragma unroll 2
    for (int tb = 0; tb < 8; ++tb) {
      bf16x8 n0 = *(const bf16x8*)(Bb + (tb + 1) * 2048 + be0);
      bf16x8 n1 = *(const bf16x8*)(Bb + (tb + 1) * 2048 + be1);
      const unsigned kh = (unsigned)((tb * 32 + lk) * 2);
      const unsigned kl = kh + 512;
      #pragma unroll
      for (int mf = 0; mf < 4; ++mf) {
        bf16x8 a = *(const bf16x8*)(sAc + ((rowb[mf] + kh) ^ swr[mf]));
        acc[mf][0] = __builtin_amdgcn_mfma_f32_16x16x32_bf16(a, b0, acc[mf][0], 0, 0, 0);
        acc[mf][1] = __builtin_amdgcn_mfma_f32_16x16x32_bf16(a, b1, acc[mf][1], 0, 0, 0);
      }
      #pragma unroll
      for (int mf = 0; mf < 4; ++mf) {
        bf16x8 a = *(const bf16x8*)(sAc + ((rowb[mf] + kl) ^ swr[mf]));
        acc[mf][0] = __builtin_amdgcn_mfma_f32_16x16x32_bf16(a, b0, acc[mf][0], 0, 0, 0);
        acc[mf][1] = __builtin_amdgcn_mfma_f32_16x16x32_bf16(a, b1, acc[mf][1], 0, 0, 0);
      }
      b0 = n0; b1 = n1;
    }
    // ---- phase B: B_lo chunks 8..15; A_hi (8 MFMA per B load)
    #pragma unroll 2
    for (int tb = 8; tb < 16; ++tb) {
      const int tbn = (tb < 15) ? tb + 1 : 15;   // clamp: avoid OOB past class
      bf16x8 n0 = *(const bf16x8*)(Bb + tbn * 2048 + be0);
      bf16x8 n1 = *(const bf16x8*)(Bb + tbn * 2048 + be1);
      const unsigned kh = (unsigned)(((tb - 8) * 32 + lk) * 2);
      #pragma unroll
      for (int mf = 0; mf < 4; ++mf) {
        bf16x8 a = *(const bf16x8*)(sAc + ((rowb[mf] + kh) ^ swr[mf]));
        acc[mf][0] = __builtin_amdgcn_mfma_f32_16x16x32_bf16(a, b0, acc[mf][0], 0, 0, 0);
        acc[mf][1] = __builtin_amdgcn_mfma_f32_16x16x32_bf16(a, b1, acc[mf][1], 0, 0, 0);
      }
      b0 = n0; b1 = n1;
    }

    // ---- epilogue: dist partials, butterfly over 16 cols, cross-wave add
    #pragma unroll
    for (int mf = 0; mf < 4; ++mf) {
      float ps[4];
      #pragma unroll
      for (int r2 = 0; r2 < 4; ++r2) {
        float t0 = acc[mf][0][r2] - gv0;
        float t1 = acc[mf][1][r2] - gv1;
        ps[r2] = fmaf(t1, t1, t0 * t0);
      }
      #pragma unroll
      for (int off = 1; off < 16; off <<= 1) {
        ps[0] += __shfl_xor(ps[0], off);
        ps[1] += __shfl_xor(ps[1], off);
        ps[2] += __shfl_xor(ps[2], off);
        ps[3] += __shfl_xor(ps[3], off);
      }
      if (l15 == 0) {
        const int rb = mh * 64 + mf * 16 + (lane >> 4) * 4;
        atomicAdd(&sP[rb + 0][clof], ps[0]);
        atomicAdd(&sP[rb + 1][clof], ps[1]);
        atomicAdd(&sP[rb + 2][clof], ps[2]);
        atomicAdd(&sP[rb + 3][clof], ps[3]);
      }
    }
    __syncthreads();
    if (tid < MT) {
      sMin[tid] = fminf(sMin[tid], fminf(sP[tid][0], sP[tid][1]));
      sP[tid][0] = 0.f; sP[tid][1] = 0.f;
    }
    __syncthreads();
  }

  if (tid < MT) out[pxbase + tid] = sMin[tid];
}

extern "C" void kernel_launch(void* const* d_in, const int* in_sizes, int n_in,
                              void* d_out, int out_size, void* d_ws, size_t ws_size,
                              hipStream_t stream) {
  const float* feats    = (const float*)d_in[0];
  const float* pca_mean = (const float*)d_in[1];
  const float* comps    = (const float*)d_in[2];
  const float* var      = (const float*)d_in[3];
  const float* mu       = (const float*)d_in[4];
  const float* cov_inv  = (const float*)d_in[5];
  float* out = (float*)d_out;

  // workspace (floats): rv[950] bc[950] L[47500] g[1280] Bs(bf16)[655360]
  float* w_rv = (float*)d_ws;
  float* w_bc = w_rv + Cc * Kk;
  float* Lmat = w_bc + Cc * Kk;
  float* gv   = Lmat + Cc * Kk * Kk;
  unsigned short* Bs = (unsigned short*)(gv + ROWS);

  const int n = in_sizes[0] / Dd;  // 131072 pixels

  prep_kernel<<<Cc, 64, 0, stream>>>(pca_mean, comps, var, mu, w_rv, w_bc);
  chol_kernel<<<Cc, 64, 0, stream>>>(cov_inv, w_bc, Lmat, gv);
  prepB_kernel<<<ROWS, 256, 0, stream>>>(comps, w_rv, Lmat, gv, Bs);
  mfma_kernel<<<n / MT, THR, 0, stream>>>(feats, Bs, gv, out);
}